// Round 1
// baseline (594.770 us; speedup 1.0000x reference)
//
#include <hip/hip_runtime.h>
#include <hip/hip_bf16.h>
#include <hip/hip_fp16.h>
#include <math.h>

#define Bn 16
#define Nn 2048
#define Cn 128

typedef __attribute__((ext_vector_type(8))) short bf16x8;   // 8 bf16 = 4 VGPRs
typedef __attribute__((ext_vector_type(4))) float f32x4;

// 0.5 / (sqrt(128) * 1.5)  -- folds symmetrization 0.5 and temperature
constexpr float SCALE = 0.029462782549439476f;
constexpr float SHIFT = 4.0f;  // fixed softmax shift; logits bounded well below this +88

__device__ __forceinline__ const bf16x8* as_frag(const __hip_bfloat16* p){
    return reinterpret_cast<const bf16x8*>(p);
}

// --- W [d][c] -> WT [c][d] so the projection kernel reads coalesced ---
__global__ __launch_bounds__(256) void transpose_w_kernel(
    const float* __restrict__ Wq, const float* __restrict__ Wk,
    float* __restrict__ WqT, float* __restrict__ WkT)
{
    int idx = blockIdx.x * 256 + threadIdx.x;  // 0..16383
    int d = idx >> 7, c = idx & 127;
    WqT[c*Cn + d] = Wq[idx];
    WkT[c*Cn + d] = Wk[idx];
}

// --- combined bias in fp16: A_stat, -inf on diagonal and where M_mask<=0 ---
__global__ __launch_bounds__(256) void prep_bias_kernel(
    const float* __restrict__ A, const float* __restrict__ M, __half* __restrict__ CB)
{
    size_t idx = (size_t)blockIdx.x * 256 + threadIdx.x;
    int n = (int)(idx >> 11), m = (int)(idx & (Nn-1));
    float a = A[idx];
    float mm = M[idx];
    float v = (mm <= 0.0f || n == m) ? -INFINITY : a;
    CB[idx] = __float2half(v);
}

// --- Q/K projection: fp32 accumulate, bf16 store. 32 rows per block. ---
__global__ __launch_bounds__(256) void qk_kernel(
    const float* __restrict__ H, const float* __restrict__ WqT, const float* __restrict__ WkT,
    __hip_bfloat16* __restrict__ Qb, __hip_bfloat16* __restrict__ Kb)
{
    __shared__ __align__(16) float Hs[32*Cn];
    const int t = threadIdx.x;
    const size_t row0 = (size_t)blockIdx.x * 32;
    const float4* src = reinterpret_cast<const float4*>(H + row0*Cn);
    float4* dst = reinterpret_cast<float4*>(Hs);
    #pragma unroll
    for (int i = 0; i < 4; i++) dst[i*256 + t] = src[i*256 + t];
    __syncthreads();
    const int d = t & 127, rh = t >> 7;
    float accq[16], acck[16];
    #pragma unroll
    for (int r = 0; r < 16; r++){ accq[r] = 0.f; acck[r] = 0.f; }
    for (int cb = 0; cb < Cn; cb += 4){
        float wq[4], wk[4];
        #pragma unroll
        for (int j = 0; j < 4; j++){ wq[j] = WqT[(cb+j)*Cn + d]; wk[j] = WkT[(cb+j)*Cn + d]; }
        #pragma unroll
        for (int r = 0; r < 16; r++){
            float4 h = *reinterpret_cast<const float4*>(&Hs[(rh*16+r)*Cn + cb]);
            accq[r] += h.x*wq[0] + h.y*wq[1] + h.z*wq[2] + h.w*wq[3];
            acck[r] += h.x*wk[0] + h.y*wk[1] + h.z*wk[2] + h.w*wk[3];
        }
    }
    #pragma unroll
    for (int r = 0; r < 16; r++){
        size_t row = row0 + rh*16 + r;
        Qb[row*Cn + d] = __float2bfloat16(accq[r]);
        Kb[row*Cn + d] = __float2bfloat16(acck[r]);
    }
}

// --- main: sym logits via MFMA; PASS 0 = row sums of exp(l-4), PASS 1 = write probs ---
// block = 256 threads = 4 waves; block tile = 64 rows (16/wave) x all 2048 cols.
template<int PASS>
__global__ __launch_bounds__(256) void attn_kernel(
    const __hip_bfloat16* __restrict__ Qb, const __hip_bfloat16* __restrict__ Kb,
    const __half* __restrict__ CB, float* __restrict__ rowsum, float* __restrict__ out)
{
    __shared__ __align__(16) __hip_bfloat16 Ks_s[64*Cn];
    __shared__ __align__(16) __hip_bfloat16 Qs_s[64*Cn];
    const int t = threadIdx.x;
    const int wave = t >> 6, lane = t & 63;
    const int q = lane >> 4, lc = lane & 15;
    const int batch = blockIdx.y;
    const int n0 = blockIdx.x * 64;
    const size_t rbase = (size_t)batch * Nn;

    // A-operand fragments for this wave's 16 rows: lane holds row (lc), k = ks*32 + q*8..+7
    const int nA = n0 + wave*16 + lc;
    bf16x8 aQ[4], aK[4];
    #pragma unroll
    for (int ks = 0; ks < 4; ks++){
        aQ[ks] = *as_frag(Qb + (rbase + nA)*Cn + ks*32 + q*8);
        aK[ks] = *as_frag(Kb + (rbase + nA)*Cn + ks*32 + q*8);
    }

    int nout[4];
    #pragma unroll
    for (int r = 0; r < 4; r++) nout[r] = n0 + wave*16 + q*4 + r;  // C/D row = q*4+reg

    float sumacc[4] = {0.f,0.f,0.f,0.f};
    float rs_inv[4];
    if (PASS == 1){
        #pragma unroll
        for (int r = 0; r < 4; r++) rs_inv[r] = 1.0f / rowsum[rbase + nout[r]];
    }

    for (int mc = 0; mc < Nn/64; mc++){
        __syncthreads();   // prev iter's LDS reads done before overwrite
        {   // stage 64-column tile of K and Q (16 KB each, coalesced 16B/lane)
            const int4* gK = reinterpret_cast<const int4*>(Kb + (rbase + (size_t)mc*64)*Cn);
            const int4* gQ = reinterpret_cast<const int4*>(Qb + (rbase + (size_t)mc*64)*Cn);
            int4* sK = reinterpret_cast<int4*>(Ks_s);
            int4* sQ = reinterpret_cast<int4*>(Qs_s);
            #pragma unroll
            for (int i = 0; i < 4; i++){ sK[i*256 + t] = gK[i*256 + t]; sQ[i*256 + t] = gQ[i*256 + t]; }
        }
        __syncthreads();
        #pragma unroll
        for (int mt = 0; mt < 4; mt++){
            const int m0 = mc*64 + mt*16;
            bf16x8 bK[4], bQ[4];
            #pragma unroll
            for (int ks = 0; ks < 4; ks++){
                bK[ks] = *as_frag(&Ks_s[(mt*16+lc)*Cn + ks*32 + q*8]);
                bQ[ks] = *as_frag(&Qs_s[(mt*16+lc)*Cn + ks*32 + q*8]);
            }
            // acc[n][m] = Qn.Km + Kn.Qm  (symmetrization folded in)
            f32x4 acc = {0.f,0.f,0.f,0.f};
            #pragma unroll
            for (int ks = 0; ks < 4; ks++){
                acc = __builtin_amdgcn_mfma_f32_16x16x32_bf16(aQ[ks], bK[ks], acc, 0, 0, 0);
                acc = __builtin_amdgcn_mfma_f32_16x16x32_bf16(aK[ks], bQ[ks], acc, 0, 0, 0);
            }
            const int m = m0 + lc;   // C/D col = lane&15
            #pragma unroll
            for (int r = 0; r < 4; r++){
                const int n = nout[r];
                float logit = fmaf(acc[r], SCALE, __half2float(CB[(size_t)n*Nn + m]));
                float e = __expf(logit - SHIFT);   // -inf -> 0
                if (PASS == 0) sumacc[r] += e;
                else out[(rbase + n)*Nn + m] = e * rs_inv[r];
            }
        }
    }
    if (PASS == 0){
        #pragma unroll
        for (int r = 0; r < 4; r++){
            float s = sumacc[r];
            s += __shfl_xor(s, 1);
            s += __shfl_xor(s, 2);
            s += __shfl_xor(s, 4);
            s += __shfl_xor(s, 8);
            if (lc == 0) rowsum[rbase + nout[r]] = s;
        }
    }
}

// ws layout (bytes):
//   [0,        8388608)   Qb   bf16 [B*N, C]
//   [8388608,  16777216)  Kb   bf16 [B*N, C]
//   [16777216, 16908288)  rowsum fp32 [B*N]
//   [16908288, 16973824)  WqT  fp32 [C, C]
//   [16973824, 17039360)  WkT  fp32 [C, C]
//   [17039360, 25427968)  CB   fp16 [N, N]
extern "C" void kernel_launch(void* const* d_in, const int* in_sizes, int n_in,
                              void* d_out, int out_size, void* d_ws, size_t ws_size,
                              hipStream_t stream)
{
    const float* H  = (const float*)d_in[0];
    const float* A  = (const float*)d_in[1];
    const float* M  = (const float*)d_in[2];
    const float* Wq = (const float*)d_in[3];
    const float* Wk = (const float*)d_in[4];
    float* out = (float*)d_out;
    char* ws = (char*)d_ws;
    __hip_bfloat16* Qb = (__hip_bfloat16*)(ws + 0);
    __hip_bfloat16* Kb = (__hip_bfloat16*)(ws + 8388608);
    float* rowsum      = (float*)(ws + 16777216);
    float* WqT         = (float*)(ws + 16908288);
    float* WkT         = (float*)(ws + 16973824);
    __half* CB         = (__half*)(ws + 17039360);

    transpose_w_kernel<<<64, 256, 0, stream>>>(Wq, Wk, WqT, WkT);
    prep_bias_kernel<<<(Nn*Nn)/256, 256, 0, stream>>>(A, M, CB);
    qk_kernel<<<(Bn*Nn)/32, 256, 0, stream>>>(H, WqT, WkT, Qb, Kb);
    attn_kernel<0><<<dim3(Nn/64, Bn), 256, 0, stream>>>(Qb, Kb, CB, rowsum, out);
    attn_kernel<1><<<dim3(Nn/64, Bn), 256, 0, stream>>>(Qb, Kb, CB, rowsum, out);
}

// Round 2
// 459.420 us; speedup vs baseline: 1.2946x; 1.2946x over previous
//
#include <hip/hip_runtime.h>
#include <hip/hip_bf16.h>
#include <hip/hip_fp16.h>
#include <math.h>

#define Bn 16
#define Nn 2048
#define Cn 128

typedef __attribute__((ext_vector_type(8))) short bf16x8;   // 8 bf16 = 4 VGPRs
typedef __attribute__((ext_vector_type(4))) float f32x4;

// 0.5 / (sqrt(128) * 1.5)  -- folds symmetrization 0.5 and temperature
constexpr float SCALE = 0.029462782549439476f;
constexpr float SHIFT = 4.0f;  // fixed softmax shift; logits bounded well below this +88

// LDS row stride in bf16 elems: 128 + 8 pad -> 272 B = 68 dwords == 4 (mod 32)
// kills the 16-way bank conflict of the unpadded 256 B (== 0 mod 32) stride.
#define LDS_STRIDE 136

__device__ __forceinline__ const bf16x8* as_frag(const __hip_bfloat16* p){
    return reinterpret_cast<const bf16x8*>(p);
}

// --- W [d][c] -> WT [c][d] so the projection kernel reads coalesced ---
__global__ __launch_bounds__(256) void transpose_w_kernel(
    const float* __restrict__ Wq, const float* __restrict__ Wk,
    float* __restrict__ WqT, float* __restrict__ WkT)
{
    int idx = blockIdx.x * 256 + threadIdx.x;  // 0..16383
    int d = idx >> 7, c = idx & 127;
    WqT[c*Cn + d] = Wq[idx];
    WkT[c*Cn + d] = Wk[idx];
}

// --- combined bias in fp16: A_stat, -inf on diagonal and where M_mask<=0 ---
__global__ __launch_bounds__(256) void prep_bias_kernel(
    const float* __restrict__ A, const float* __restrict__ M, __half* __restrict__ CB)
{
    size_t idx = (size_t)blockIdx.x * 256 + threadIdx.x;
    int n = (int)(idx >> 11), m = (int)(idx & (Nn-1));
    float a = A[idx];
    float mm = M[idx];
    float v = (mm <= 0.0f || n == m) ? -INFINITY : a;
    CB[idx] = __float2half(v);
}

// --- Q/K projection: fp32 accumulate, bf16 store. 32 rows per block. ---
__global__ __launch_bounds__(256) void qk_kernel(
    const float* __restrict__ H, const float* __restrict__ WqT, const float* __restrict__ WkT,
    __hip_bfloat16* __restrict__ Qb, __hip_bfloat16* __restrict__ Kb)
{
    __shared__ __align__(16) float Hs[32*Cn];
    const int t = threadIdx.x;
    const size_t row0 = (size_t)blockIdx.x * 32;
    const float4* src = reinterpret_cast<const float4*>(H + row0*Cn);
    float4* dst = reinterpret_cast<float4*>(Hs);
    #pragma unroll
    for (int i = 0; i < 4; i++) dst[i*256 + t] = src[i*256 + t];
    __syncthreads();
    const int d = t & 127, rh = t >> 7;
    float accq[16], acck[16];
    #pragma unroll
    for (int r = 0; r < 16; r++){ accq[r] = 0.f; acck[r] = 0.f; }
    for (int cb = 0; cb < Cn; cb += 4){
        float wq[4], wk[4];
        #pragma unroll
        for (int j = 0; j < 4; j++){ wq[j] = WqT[(cb+j)*Cn + d]; wk[j] = WkT[(cb+j)*Cn + d]; }
        #pragma unroll
        for (int r = 0; r < 16; r++){
            float4 h = *reinterpret_cast<const float4*>(&Hs[(rh*16+r)*Cn + cb]);
            accq[r] += h.x*wq[0] + h.y*wq[1] + h.z*wq[2] + h.w*wq[3];
            acck[r] += h.x*wk[0] + h.y*wk[1] + h.z*wk[2] + h.w*wk[3];
        }
    }
    #pragma unroll
    for (int r = 0; r < 16; r++){
        size_t row = row0 + rh*16 + r;
        Qb[row*Cn + d] = __float2bfloat16(accq[r]);
        Kb[row*Cn + d] = __float2bfloat16(acck[r]);
    }
}

// --- main: sym logits via MFMA; PASS 0 = row sums of exp(l-4), PASS 1 = write probs ---
// block = 256 threads = 4 waves; block tile = 64 rows (16/wave) x all 2048 cols.
template<int PASS>
__global__ __launch_bounds__(256) void attn_kernel(
    const __hip_bfloat16* __restrict__ Qb, const __hip_bfloat16* __restrict__ Kb,
    const __half* __restrict__ CB, float* __restrict__ rowsum, float* __restrict__ out)
{
    __shared__ __align__(16) __hip_bfloat16 Ks_s[64*LDS_STRIDE];
    __shared__ __align__(16) __hip_bfloat16 Qs_s[64*LDS_STRIDE];
    const int t = threadIdx.x;
    const int wave = t >> 6, lane = t & 63;
    const int q = lane >> 4, lc = lane & 15;
    const int batch = blockIdx.y;
    const int n0 = blockIdx.x * 64;
    const size_t rbase = (size_t)batch * Nn;

    // A-operand fragments for this wave's 16 rows: lane holds row (lc), k = ks*32 + q*8..+7
    const int nA = n0 + wave*16 + lc;
    bf16x8 aQ[4], aK[4];
    #pragma unroll
    for (int ks = 0; ks < 4; ks++){
        aQ[ks] = *as_frag(Qb + (rbase + nA)*Cn + ks*32 + q*8);
        aK[ks] = *as_frag(Kb + (rbase + nA)*Cn + ks*32 + q*8);
    }

    int nout[4];
    #pragma unroll
    for (int r = 0; r < 4; r++) nout[r] = n0 + wave*16 + q*4 + r;  // C/D row = q*4+reg

    float sumacc[4] = {0.f,0.f,0.f,0.f};
    float rs_inv[4];
    if (PASS == 1){
        #pragma unroll
        for (int r = 0; r < 4; r++) rs_inv[r] = 1.0f / rowsum[rbase + nout[r]];
    }

    for (int mc = 0; mc < Nn/64; mc++){
        __syncthreads();   // prev iter's LDS reads done before overwrite
        {   // stage 64-col tile of K and Q: 1024 16-B chunks each, 4 per thread.
            // global reads coalesced (consecutive ids); LDS writes at padded stride.
            const int4* gK = reinterpret_cast<const int4*>(Kb + (rbase + (size_t)mc*64)*Cn);
            const int4* gQ = reinterpret_cast<const int4*>(Qb + (rbase + (size_t)mc*64)*Cn);
            #pragma unroll
            for (int i = 0; i < 4; i++){
                int id = i*256 + t;              // 0..1023
                int r = id >> 4, c2 = id & 15;   // row in tile, 16B chunk in row
                int4 vk = gK[id];
                int4 vq = gQ[id];
                *reinterpret_cast<int4*>(&Ks_s[r*LDS_STRIDE + c2*8]) = vk;
                *reinterpret_cast<int4*>(&Qs_s[r*LDS_STRIDE + c2*8]) = vq;
            }
        }
        __syncthreads();
        #pragma unroll
        for (int mt = 0; mt < 4; mt++){
            const int m0 = mc*64 + mt*16;
            bf16x8 bK[4], bQ[4];
            #pragma unroll
            for (int ks = 0; ks < 4; ks++){
                bK[ks] = *as_frag(&Ks_s[(mt*16+lc)*LDS_STRIDE + ks*32 + q*8]);
                bQ[ks] = *as_frag(&Qs_s[(mt*16+lc)*LDS_STRIDE + ks*32 + q*8]);
            }
            // acc[n][m] = Qn.Km + Kn.Qm  (symmetrization folded in)
            f32x4 acc = {0.f,0.f,0.f,0.f};
            #pragma unroll
            for (int ks = 0; ks < 4; ks++){
                acc = __builtin_amdgcn_mfma_f32_16x16x32_bf16(aQ[ks], bK[ks], acc, 0, 0, 0);
                acc = __builtin_amdgcn_mfma_f32_16x16x32_bf16(aK[ks], bQ[ks], acc, 0, 0, 0);
            }
            const int m = m0 + lc;   // C/D col = lane&15
            #pragma unroll
            for (int r = 0; r < 4; r++){
                const int n = nout[r];
                float logit = fmaf(acc[r], SCALE, __half2float(CB[(size_t)n*Nn + m]));
                float e = __expf(logit - SHIFT);   // -inf -> 0
                if (PASS == 0) sumacc[r] += e;
                else out[(rbase + n)*Nn + m] = e * rs_inv[r];
            }
        }
    }
    if (PASS == 0){
        #pragma unroll
        for (int r = 0; r < 4; r++){
            float s = sumacc[r];
            s += __shfl_xor(s, 1);
            s += __shfl_xor(s, 2);
            s += __shfl_xor(s, 4);
            s += __shfl_xor(s, 8);
            if (lc == 0) rowsum[rbase + nout[r]] = s;
        }
    }
}

// ws layout (bytes):
//   [0,        8388608)   Qb   bf16 [B*N, C]
//   [8388608,  16777216)  Kb   bf16 [B*N, C]
//   [16777216, 16908288)  rowsum fp32 [B*N]
//   [16908288, 16973824)  WqT  fp32 [C, C]
//   [16973824, 17039360)  WkT  fp32 [C, C]
//   [17039360, 25427968)  CB   fp16 [N, N]
extern "C" void kernel_launch(void* const* d_in, const int* in_sizes, int n_in,
                              void* d_out, int out_size, void* d_ws, size_t ws_size,
                              hipStream_t stream)
{
    const float* H  = (const float*)d_in[0];
    const float* A  = (const float*)d_in[1];
    const float* M  = (const float*)d_in[2];
    const float* Wq = (const float*)d_in[3];
    const float* Wk = (const float*)d_in[4];
    float* out = (float*)d_out;
    char* ws = (char*)d_ws;
    __hip_bfloat16* Qb = (__hip_bfloat16*)(ws + 0);
    __hip_bfloat16* Kb = (__hip_bfloat16*)(ws + 8388608);
    float* rowsum      = (float*)(ws + 16777216);
    float* WqT         = (float*)(ws + 16908288);
    float* WkT         = (float*)(ws + 16973824);
    __half* CB         = (__half*)(ws + 17039360);

    transpose_w_kernel<<<64, 256, 0, stream>>>(Wq, Wk, WqT, WkT);
    prep_bias_kernel<<<(Nn*Nn)/256, 256, 0, stream>>>(A, M, CB);
    qk_kernel<<<(Bn*Nn)/32, 256, 0, stream>>>(H, WqT, WkT, Qb, Kb);
    attn_kernel<0><<<dim3(Nn/64, Bn), 256, 0, stream>>>(Qb, Kb, CB, rowsum, out);
    attn_kernel<1><<<dim3(Nn/64, Bn), 256, 0, stream>>>(Qb, Kb, CB, rowsum, out);
}